// Round 1
// baseline (2198.590 us; speedup 1.0000x reference)
//
#include <hip/hip_runtime.h>
#include <hip/hip_bf16.h>
#include <cstdint>

#define BDIM  2
#define TSEQ  2048
#define CDIM  1024
#define NHEAD 16
#define HDIM  64
#define KTILE 32

// ---------------------------------------------------------------------------
// GEMM:  C[m][n] = sum_k A[m][k] * B[n][k] + bias[n]     (C = A @ B^T + bias)
// A: MxK row-major, B: NxK row-major, C: MxN row-major.
// BM=BN=128, BK=16, 256 threads, 8x8 per thread (4+4 split).
// ---------------------------------------------------------------------------
__global__ __launch_bounds__(256, 2) void gemm_nt_bias(
    const float* __restrict__ A, const float* __restrict__ B,
    const float* __restrict__ bias, float* __restrict__ C,
    int M, int N, int K)
{
  // +4 pad keeps 16B alignment (132 floats = 528B = 33*16) and breaks strides.
  __shared__ float As[16][132];
  __shared__ float Bs[16][132];

  const int tid = threadIdx.x;
  const int tx  = tid & 15;   // 0..15 -> N dim
  const int ty  = tid >> 4;   // 0..15 -> M dim
  const int bn  = blockIdx.x;
  const int bm  = blockIdx.y;

  const float* Ap = A + (size_t)bm * 128 * K;
  const float* Bp = B + (size_t)bn * 128 * K;

  float acc[8][8];
#pragma unroll
  for (int i = 0; i < 8; ++i)
#pragma unroll
    for (int j = 0; j < 8; ++j) acc[i][j] = 0.0f;

  for (int k0 = 0; k0 < K; k0 += 16) {
    // Load 128x16 A-tile and B-tile, store transposed [k][m] into LDS.
#pragma unroll
    for (int i = 0; i < 2; ++i) {
      const int f  = tid + i * 256;      // 0..511 float4 slots
      const int r  = f >> 2;             // 0..127 tile row
      const int c4 = (f & 3) << 2;       // 0,4,8,12 k-offset
      const float4 va = *(const float4*)(Ap + (size_t)r * K + k0 + c4);
      const float4 vb = *(const float4*)(Bp + (size_t)r * K + k0 + c4);
      As[c4 + 0][r] = va.x; As[c4 + 1][r] = va.y;
      As[c4 + 2][r] = va.z; As[c4 + 3][r] = va.w;
      Bs[c4 + 0][r] = vb.x; Bs[c4 + 1][r] = vb.y;
      Bs[c4 + 2][r] = vb.z; Bs[c4 + 3][r] = vb.w;
    }
    __syncthreads();

#pragma unroll
    for (int k = 0; k < 16; ++k) {
      const float4 a0 = *(const float4*)&As[k][ty * 4];
      const float4 a1 = *(const float4*)&As[k][64 + ty * 4];
      const float4 b0 = *(const float4*)&Bs[k][tx * 4];
      const float4 b1 = *(const float4*)&Bs[k][64 + tx * 4];
      const float ra[8] = {a0.x, a0.y, a0.z, a0.w, a1.x, a1.y, a1.z, a1.w};
      const float rb[8] = {b0.x, b0.y, b0.z, b0.w, b1.x, b1.y, b1.z, b1.w};
#pragma unroll
      for (int i = 0; i < 8; ++i)
#pragma unroll
        for (int j = 0; j < 8; ++j)
          acc[i][j] = fmaf(ra[i], rb[j], acc[i][j]);
    }
    __syncthreads();
  }

  // Epilogue: bias + store (rows ty*4 / 64+ty*4, cols tx*4 / 64+tx*4).
  const int row0 = bm * 128;
  const int col0 = bn * 128;
  const float4 bi0 = *(const float4*)(bias + col0 + tx * 4);
  const float4 bi1 = *(const float4*)(bias + col0 + 64 + tx * 4);
#pragma unroll
  for (int i = 0; i < 8; ++i) {
    const int r = row0 + ((i < 4) ? (ty * 4 + i) : (64 + ty * 4 + (i - 4)));
    float* crow = C + (size_t)r * N + col0;
    float4 o0, o1;
    o0.x = acc[i][0] + bi0.x; o0.y = acc[i][1] + bi0.y;
    o0.z = acc[i][2] + bi0.z; o0.w = acc[i][3] + bi0.w;
    o1.x = acc[i][4] + bi1.x; o1.y = acc[i][5] + bi1.y;
    o1.z = acc[i][6] + bi1.z; o1.w = acc[i][7] + bi1.w;
    *(float4*)(crow + tx * 4)      = o0;
    *(float4*)(crow + 64 + tx * 4) = o1;
  }
}

// ---------------------------------------------------------------------------
// Causal flash attention, fp32. One Q-row per thread; Q and O live in
// registers; K/V tiles staged in LDS and read broadcast (lockstep j).
// qkv layout: [B*T][3*C], q at +0, k at +C, v at +2C, head h at +h*64.
// y layout: [B*T][C] (b,t,h,d).
// grid: (TSEQ/256, NHEAD, BDIM), block: 256.
// ---------------------------------------------------------------------------
__global__ __launch_bounds__(256, 1) void attn_fwd(
    const float* __restrict__ qkv, float* __restrict__ y)
{
  const int qt = blockIdx.x;            // q-tile of 256 rows
  const int h  = blockIdx.y;
  const int b  = blockIdx.z;
  const int r  = qt * 256 + threadIdx.x;   // this thread's q row (in [0,T))

  const size_t row3c = (size_t)3 * CDIM;
  const float* qptr  = qkv + ((size_t)(b * TSEQ + r)) * row3c + h * HDIM;
  const float* kbase = qkv + ((size_t)(b * TSEQ)) * row3c + CDIM + h * HDIM;
  const float* vbase = kbase + CDIM;

  float q[HDIM];
#pragma unroll
  for (int i = 0; i < HDIM / 4; ++i)
    ((float4*)q)[i] = ((const float4*)qptr)[i];

  float O[HDIM];
#pragma unroll
  for (int d = 0; d < HDIM; ++d) O[d] = 0.0f;
  float m = -3.0e38f, l = 0.0f;

  __shared__ float Ks[KTILE][HDIM];
  __shared__ float Vs[KTILE][HDIM];

  const int kend = qt * 256 + 256;      // max K row needed by this block (+1)

  for (int k0 = 0; k0 < kend; k0 += KTILE) {
    __syncthreads();   // previous iteration's readers are done
    // Cooperative load of K/V tile: KTILE*64 floats = 512 float4 each.
#pragma unroll
    for (int i = 0; i < 2; ++i) {
      const int f   = threadIdx.x + i * 256;  // 0..511
      const int row = f >> 4;                 // 0..31
      const int c4  = (f & 15) << 2;          // 0..60
      *(float4*)&Ks[row][c4] =
          *(const float4*)(kbase + (size_t)(k0 + row) * row3c + c4);
      *(float4*)&Vs[row][c4] =
          *(const float4*)(vbase + (size_t)(k0 + row) * row3c + c4);
    }
    __syncthreads();

    if (k0 > r) continue;   // fully masked for this thread (barriers already hit)

    float s[KTILE];
    float mt = -3.0e38f;
#pragma unroll
    for (int j = 0; j < KTILE; ++j) {
      const float4* krow = (const float4*)Ks[j];
      float p0 = 0.f, p1 = 0.f, p2 = 0.f, p3 = 0.f;
#pragma unroll
      for (int d4 = 0; d4 < HDIM / 4; ++d4) {
        const float4 kv = krow[d4];
        p0 = fmaf(q[d4 * 4 + 0], kv.x, p0);
        p1 = fmaf(q[d4 * 4 + 1], kv.y, p1);
        p2 = fmaf(q[d4 * 4 + 2], kv.z, p2);
        p3 = fmaf(q[d4 * 4 + 3], kv.w, p3);
      }
      float sv = ((p0 + p1) + (p2 + p3)) * 0.125f;   // 1/sqrt(64)
      sv = (k0 + j <= r) ? sv : -3.0e38f;
      s[j] = sv;
      mt = fmaxf(mt, sv);
    }

    const float mnew  = fmaxf(m, mt);
    const float alpha = __expf(m - mnew);
    l *= alpha;
#pragma unroll
    for (int d = 0; d < HDIM; ++d) O[d] *= alpha;
    m = mnew;

#pragma unroll
    for (int j = 0; j < KTILE; ++j) {
      const float p = __expf(s[j] - m);
      l += p;
      const float4* vrow = (const float4*)Vs[j];
#pragma unroll
      for (int d4 = 0; d4 < HDIM / 4; ++d4) {
        const float4 vv = vrow[d4];
        O[d4 * 4 + 0] = fmaf(p, vv.x, O[d4 * 4 + 0]);
        O[d4 * 4 + 1] = fmaf(p, vv.y, O[d4 * 4 + 1]);
        O[d4 * 4 + 2] = fmaf(p, vv.z, O[d4 * 4 + 2]);
        O[d4 * 4 + 3] = fmaf(p, vv.w, O[d4 * 4 + 3]);
      }
    }
  }

  const float inv = 1.0f / l;
  float* yrow = y + ((size_t)(b * TSEQ + r)) * CDIM + h * HDIM;
#pragma unroll
  for (int d4 = 0; d4 < HDIM / 4; ++d4) {
    float4 o;
    o.x = O[d4 * 4 + 0] * inv; o.y = O[d4 * 4 + 1] * inv;
    o.z = O[d4 * 4 + 2] * inv; o.w = O[d4 * 4 + 3] * inv;
    *(float4*)(yrow + d4 * 4) = o;
  }
}

// ---------------------------------------------------------------------------
extern "C" void kernel_launch(void* const* d_in, const int* in_sizes, int n_in,
                              void* d_out, int out_size, void* d_ws, size_t ws_size,
                              hipStream_t stream)
{
  const float* x     = (const float*)d_in[0];   // [B,T,C]
  const float* Wqkv  = (const float*)d_in[1];   // [3C,C]
  const float* bqkv  = (const float*)d_in[2];   // [3C]
  const float* Wproj = (const float*)d_in[3];   // [C,C]
  const float* bproj = (const float*)d_in[4];   // [C]
  float* out = (float*)d_out;                   // [B,T,C]

  const int M = BDIM * TSEQ;                    // 4096
  float* qkv = (float*)d_ws;                    // M x 3C  (48 MB)
  float* yb  = qkv + (size_t)M * 3 * CDIM;      // M x C   (16 MB)

  // 1) qkv = x @ Wqkv^T + bqkv
  {
    dim3 grid(3 * CDIM / 128, M / 128);
    gemm_nt_bias<<<grid, 256, 0, stream>>>(x, Wqkv, bqkv, qkv, M, 3 * CDIM, CDIM);
  }
  // 2) causal attention -> yb (b,t,h,d)
  {
    dim3 grid(TSEQ / 256, NHEAD, BDIM);
    attn_fwd<<<grid, 256, 0, stream>>>(qkv, yb);
  }
  // 3) out = yb @ Wproj^T + bproj
  {
    dim3 grid(CDIM / 128, M / 128);
    gemm_nt_bias<<<grid, 256, 0, stream>>>(yb, Wproj, bproj, out, M, CDIM, CDIM);
  }
}

// Round 2
// 239.419 us; speedup vs baseline: 9.1830x; 9.1830x over previous
//
#include <hip/hip_runtime.h>
#include <cstdint>

#define BDIM  2
#define TSEQ  2048
#define CDIM  1024
#define NHEAD 16
#define HDIM  64
#define C3    3072

typedef __attribute__((ext_vector_type(8))) short short8_t;
typedef __attribute__((ext_vector_type(4))) float f32x4;

static __device__ __forceinline__ unsigned short f2bf(float f) {
  union { float f; unsigned u; } v; v.f = f;
  unsigned r = v.u + 0x7FFFu + ((v.u >> 16) & 1u);   // RNE
  return (unsigned short)(r >> 16);
}

// ---- swizzled LDS element-index helpers (ushort arrays) -------------------
// GEMM tiles: [128 rows][32 k] bf16, 16B chunks 0..3, chunk ^= (row>>1)&3
__device__ __forceinline__ int gemm_idx(int row, int chunk) {
  return row * 32 + (((chunk ^ ((row >> 1) & 3)) & 3) << 3);
}
// K tile: [32 kv][64 d] bf16, chunks 0..7 (d>>3), chunk ^= kv&7
__device__ __forceinline__ int k_idx(int kv, int chunk) {
  return kv * 64 + (((chunk ^ (kv & 7)) & 7) << 3);
}
// V^T tile: [64 d][32 kv] bf16, chunks 0..3 (kv>>3), chunk ^= (d^(d>>3))&3
__device__ __forceinline__ int vt_idx(int d, int chunk) {
  return d * 32 + (((chunk ^ ((d ^ (d >> 3)) & 3)) & 3) << 3);
}

// ---------------------------------------------------------------------------
// C[m][n] = sum_k A[m][k]*B[n][k] + bias[n]   (A: MxK, B: NxK, C: MxN)
// bf16 MFMA 16x16x32, 128x128 tile, 4 waves, 4x4 frags/wave, BK=32.
// ---------------------------------------------------------------------------
template <bool A_BF16, bool OUT_BF16>
__global__ __launch_bounds__(256, 2) void gemm_bt_mfma(
    const void* __restrict__ Av, const float* __restrict__ B,
    const float* __restrict__ bias, void* __restrict__ Cv,
    int M, int N, int K)
{
  __shared__ unsigned short As[128 * 32];
  __shared__ unsigned short Bs[128 * 32];

  const int tid  = threadIdx.x;
  const int lane = tid & 63;
  const int wv   = tid >> 6;
  const int wr   = wv >> 1, wc = wv & 1;
  const int l15  = lane & 15, g = lane >> 4;
  const int bn = blockIdx.x, bm = blockIdx.y;

  const int srow = tid >> 1;   // staging row 0..127
  const int sh   = tid & 1;    // which 16-k half

  f32x4 acc[4][4];
#pragma unroll
  for (int i = 0; i < 4; ++i)
#pragma unroll
    for (int j = 0; j < 4; ++j) acc[i][j] = (f32x4){0.f, 0.f, 0.f, 0.f};

  for (int k0 = 0; k0 < K; k0 += 32) {
    __syncthreads();
    unsigned short ta[16], tb[16];
    if (A_BF16) {
      const unsigned short* src =
          (const unsigned short*)Av + (size_t)(bm * 128 + srow) * K + k0 + sh * 16;
      *(short8_t*)(ta + 0) = *(const short8_t*)(src + 0);
      *(short8_t*)(ta + 8) = *(const short8_t*)(src + 8);
    } else {
      const float* src = (const float*)Av + (size_t)(bm * 128 + srow) * K + k0 + sh * 16;
#pragma unroll
      for (int e = 0; e < 16; e += 4) {
        float4 v = *(const float4*)(src + e);
        ta[e + 0] = f2bf(v.x); ta[e + 1] = f2bf(v.y);
        ta[e + 2] = f2bf(v.z); ta[e + 3] = f2bf(v.w);
      }
    }
    {
      const float* src = B + (size_t)(bn * 128 + srow) * K + k0 + sh * 16;
#pragma unroll
      for (int e = 0; e < 16; e += 4) {
        float4 v = *(const float4*)(src + e);
        tb[e + 0] = f2bf(v.x); tb[e + 1] = f2bf(v.y);
        tb[e + 2] = f2bf(v.z); tb[e + 3] = f2bf(v.w);
      }
    }
#pragma unroll
    for (int w = 0; w < 2; ++w) {
      *(short8_t*)&As[gemm_idx(srow, sh * 2 + w)] = *(short8_t*)(ta + w * 8);
      *(short8_t*)&Bs[gemm_idx(srow, sh * 2 + w)] = *(short8_t*)(tb + w * 8);
    }
    __syncthreads();

    short8_t af[4], bf[4];
#pragma unroll
    for (int i = 0; i < 4; ++i) {
      const int row = wr * 64 + i * 16 + l15;
      af[i] = *(const short8_t*)&As[gemm_idx(row, g)];
    }
#pragma unroll
    for (int j = 0; j < 4; ++j) {
      const int row = wc * 64 + j * 16 + l15;
      bf[j] = *(const short8_t*)&Bs[gemm_idx(row, g)];
    }
#pragma unroll
    for (int i = 0; i < 4; ++i)
#pragma unroll
      for (int j = 0; j < 4; ++j)
        acc[i][j] = __builtin_amdgcn_mfma_f32_16x16x32_bf16(af[i], bf[j], acc[i][j], 0, 0, 0);
  }

  // epilogue: D row = g*4+r, col = l15 within each 16x16 frag
#pragma unroll
  for (int j = 0; j < 4; ++j) {
    const int col = bn * 128 + wc * 64 + j * 16 + l15;
    const float bj = bias[col];
#pragma unroll
    for (int i = 0; i < 4; ++i) {
#pragma unroll
      for (int r = 0; r < 4; ++r) {
        const int row = bm * 128 + wr * 64 + i * 16 + g * 4 + r;
        const float v = acc[i][j][r] + bj;
        if (OUT_BF16) ((unsigned short*)Cv)[(size_t)row * N + col] = f2bf(v);
        else          ((float*)Cv)[(size_t)row * N + col] = v;
      }
    }
  }
}

// ---------------------------------------------------------------------------
// Causal flash attention, bf16 MFMA. Block = 4 waves = 128 q-rows of one
// (b,h); wave handles 32 q-rows. KV tiles of 32 staged in LDS (K row-major
// swizzled, V transposed+swizzled). Softmax fp32 in registers; P via
// per-wave LDS to convert D-layout -> A-layout.
// qkv: [B*T][3C] bf16 (q +0, k +C, v +2C, head h at +h*64). yb: [B*T][C] bf16.
// ---------------------------------------------------------------------------
__global__ __launch_bounds__(256, 2) void attn_mfma(
    const unsigned short* __restrict__ qkv, unsigned short* __restrict__ yb)
{
  __shared__ unsigned short Ks[32 * 64];
  __shared__ unsigned short Vt[64 * 32];
  __shared__ unsigned short Ps[4 * 32 * 40];   // per-wave [32 q][40] (pad)

  const int tid  = threadIdx.x;
  const int lane = tid & 63;
  const int wv   = tid >> 6;
  const int l15  = lane & 15, g = lane >> 4;
  const int qt_raw = blockIdx.x, h = blockIdx.y, b = blockIdx.z;
  // reverse q-tile order for b=1 so each CU pairs a heavy + light block
  const int qt  = (b == 0) ? qt_raw : ((int)gridDim.x - 1 - qt_raw);
  const int wq0 = qt * 128 + wv * 32;

  const unsigned short* kbase = qkv + (size_t)(b * TSEQ) * C3 + CDIM + h * HDIM;
  const unsigned short* vbase = kbase + CDIM;

  // Q fragments (A-layout: row=l15, k=g*8+j), m in {0,1}, kk in {0,1}
  short8_t qf[2][2];
#pragma unroll
  for (int m = 0; m < 2; ++m)
#pragma unroll
    for (int kk = 0; kk < 2; ++kk)
      qf[m][kk] = *(const short8_t*)(qkv +
          (size_t)(b * TSEQ + wq0 + m * 16 + l15) * C3 + h * HDIM + kk * 32 + g * 8);

  f32x4 O[2][4];
#pragma unroll
  for (int m = 0; m < 2; ++m)
#pragma unroll
    for (int n = 0; n < 4; ++n) O[m][n] = (f32x4){0.f, 0.f, 0.f, 0.f};
  float Mr[2][4], Lr[2][4];
#pragma unroll
  for (int m = 0; m < 2; ++m)
#pragma unroll
    for (int r = 0; r < 4; ++r) { Mr[m][r] = -3.0e38f; Lr[m][r] = 0.f; }

  unsigned short* Pw = &Ps[wv * 32 * 40];
  const int kend = qt * 128 + 128;

  for (int kv0 = 0; kv0 < kend; kv0 += 32) {
    __syncthreads();
    {
      // stage K (row-copy, swizzled) and V^T (scatter, swizzled)
      const int kv = tid >> 3, a = tid & 7;
      const size_t rowoff = (size_t)(kv0 + kv) * C3 + a * 8;
      *(short8_t*)&Ks[k_idx(kv, a)] = *(const short8_t*)(kbase + rowoff);
      short8_t vvv = *(const short8_t*)(vbase + rowoff);
      const unsigned short* pv = (const unsigned short*)&vvv;
#pragma unroll
      for (int j = 0; j < 8; ++j) {
        const int d = a * 8 + j;
        Vt[vt_idx(d, kv >> 3) + (kv & 7)] = pv[j];
      }
    }
    __syncthreads();
    if (kv0 > wq0 + 31) continue;          // wave-uniform skip

    // S = Q K^T  (D-layout: row(q)=g*4+r, col(kv)=l15)
    f32x4 s[2][2];
#pragma unroll
    for (int m = 0; m < 2; ++m)
#pragma unroll
      for (int n = 0; n < 2; ++n) s[m][n] = (f32x4){0.f, 0.f, 0.f, 0.f};
#pragma unroll
    for (int kk = 0; kk < 2; ++kk) {
      short8_t kf[2];
#pragma unroll
      for (int n = 0; n < 2; ++n) {
        const int kr = n * 16 + l15;
        kf[n] = *(const short8_t*)&Ks[k_idx(kr, kk * 4 + g)];
      }
#pragma unroll
      for (int m = 0; m < 2; ++m)
#pragma unroll
        for (int n = 0; n < 2; ++n)
          s[m][n] = __builtin_amdgcn_mfma_f32_16x16x32_bf16(qf[m][kk], kf[n], s[m][n], 0, 0, 0);
    }

    // scale + causal mask
    const bool partial = (kv0 + 31 > wq0);
#pragma unroll
    for (int m = 0; m < 2; ++m)
#pragma unroll
      for (int n = 0; n < 2; ++n)
#pragma unroll
        for (int r = 0; r < 4; ++r) {
          float v = s[m][n][r] * 0.125f;
          if (partial) {
            const int qg  = wq0 + m * 16 + g * 4 + r;
            const int kvg = kv0 + n * 16 + l15;
            if (kvg > qg) v = -3.0e38f;
          }
          s[m][n][r] = v;
        }

    // online softmax (per q-row: reduce over n regs + 16 lanes)
#pragma unroll
    for (int m = 0; m < 2; ++m) {
      float mt[4], al[4];
#pragma unroll
      for (int r = 0; r < 4; ++r) mt[r] = fmaxf(s[m][0][r], s[m][1][r]);
#pragma unroll
      for (int off = 1; off < 16; off <<= 1)
#pragma unroll
        for (int r = 0; r < 4; ++r) mt[r] = fmaxf(mt[r], __shfl_xor(mt[r], off));
#pragma unroll
      for (int r = 0; r < 4; ++r) {
        const float nm = fmaxf(Mr[m][r], mt[r]);
        al[r] = __expf(Mr[m][r] - nm);
        Mr[m][r] = nm;
      }
#pragma unroll
      for (int n = 0; n < 2; ++n)
#pragma unroll
        for (int r = 0; r < 4; ++r) s[m][n][r] = __expf(s[m][n][r] - Mr[m][r]);
      float rs[4];
#pragma unroll
      for (int r = 0; r < 4; ++r) rs[r] = s[m][0][r] + s[m][1][r];
#pragma unroll
      for (int off = 1; off < 16; off <<= 1)
#pragma unroll
        for (int r = 0; r < 4; ++r) rs[r] += __shfl_xor(rs[r], off);
#pragma unroll
      for (int r = 0; r < 4; ++r) Lr[m][r] = Lr[m][r] * al[r] + rs[r];
#pragma unroll
      for (int n = 0; n < 4; ++n)
#pragma unroll
        for (int r = 0; r < 4; ++r) O[m][n][r] *= al[r];
      // P (bf16) to per-wave LDS in [q][kv] order
#pragma unroll
      for (int n = 0; n < 2; ++n)
#pragma unroll
        for (int r = 0; r < 4; ++r)
          Pw[(m * 16 + g * 4 + r) * 40 + n * 16 + l15] = f2bf(s[m][n][r]);
    }

    // PV: A = P (row=l15, k(kv)=g*8+j), B = V^T frag (col(d)=l15)
    short8_t vf[4];
#pragma unroll
    for (int n = 0; n < 4; ++n) {
      const int d = n * 16 + l15;
      vf[n] = *(const short8_t*)&Vt[vt_idx(d, g)];
    }
#pragma unroll
    for (int m = 0; m < 2; ++m) {
      const short8_t pf = *(const short8_t*)&Pw[(m * 16 + l15) * 40 + g * 8];
#pragma unroll
      for (int n = 0; n < 4; ++n)
        O[m][n] = __builtin_amdgcn_mfma_f32_16x16x32_bf16(pf, vf[n], O[m][n], 0, 0, 0);
    }
  }

  // epilogue: O/L -> bf16, row = g*4+r matches Lr
#pragma unroll
  for (int m = 0; m < 2; ++m) {
    float inv[4];
#pragma unroll
    for (int r = 0; r < 4; ++r) inv[r] = 1.0f / Lr[m][r];
#pragma unroll
    for (int n = 0; n < 4; ++n)
#pragma unroll
      for (int r = 0; r < 4; ++r) {
        const size_t row = (size_t)(b * TSEQ + wq0 + m * 16 + g * 4 + r);
        yb[row * CDIM + h * HDIM + n * 16 + l15] = f2bf(O[m][n][r] * inv[r]);
      }
  }
}

// ---------------------------------------------------------------------------
extern "C" void kernel_launch(void* const* d_in, const int* in_sizes, int n_in,
                              void* d_out, int out_size, void* d_ws, size_t ws_size,
                              hipStream_t stream)
{
  const float* x     = (const float*)d_in[0];   // [B,T,C] fp32
  const float* Wqkv  = (const float*)d_in[1];   // [3C,C]  fp32
  const float* bqkv  = (const float*)d_in[2];   // [3C]
  const float* Wproj = (const float*)d_in[3];   // [C,C]
  const float* bproj = (const float*)d_in[4];   // [C]
  float* out = (float*)d_out;                   // [B,T,C] fp32

  const int M = BDIM * TSEQ;                    // 4096
  unsigned short* qkv = (unsigned short*)d_ws;  // M x 3C bf16 (24 MB)
  unsigned short* yb  = qkv + (size_t)M * C3;   // M x C  bf16 (8 MB)

  // 1) qkv = bf16(x @ Wqkv^T + bqkv)
  gemm_bt_mfma<false, true><<<dim3(C3 / 128, M / 128), 256, 0, stream>>>(
      (const void*)x, Wqkv, bqkv, (void*)qkv, M, C3, CDIM);

  // 2) causal attention -> yb (bf16)
  attn_mfma<<<dim3(TSEQ / 128, NHEAD, BDIM), 256, 0, stream>>>(qkv, yb);

  // 3) out = yb @ Wproj^T + bproj (fp32 out)
  gemm_bt_mfma<true, false><<<dim3(CDIM / 128, M / 128), 256, 0, stream>>>(
      (const void*)yb, Wproj, bproj, (void*)out, M, CDIM, CDIM);
}

// Round 3
// 198.695 us; speedup vs baseline: 11.0651x; 1.2050x over previous
//
#include <hip/hip_runtime.h>
#include <cstdint>

#define BDIM  2
#define TSEQ  2048
#define CDIM  1024
#define NHEAD 16
#define HDIM  64
#define C3    3072

typedef __attribute__((ext_vector_type(8))) short short8_t;
typedef __attribute__((ext_vector_type(4))) float f32x4;

static __device__ __forceinline__ unsigned short f2bf(float f) {
  union { float f; unsigned u; } v; v.f = f;
  unsigned r = v.u + 0x7FFFu + ((v.u >> 16) & 1u);   // RNE
  return (unsigned short)(r >> 16);
}

// GEMM tiles: [128 rows][32 k] bf16, 16B chunks 0..3, chunk ^= (row>>1)&3
__device__ __forceinline__ int gemm_idx(int row, int chunk) {
  return row * 32 + (((chunk ^ ((row >> 1) & 3)) & 3) << 3);
}
// attn K tile: [64 kv][64 d] bf16, chunks 0..7 (d>>3), chunk ^= kv&7
__device__ __forceinline__ int kk_idx(int kv, int chunk) {
  return kv * 64 + (((chunk ^ (kv & 7)) & 7) << 3);
}
// attn V^T tile: [64 d][64 kv] bf16, chunks 0..7 (kv>>3),
// chunk ^= (d&7) ^ ((d>>3)&7)  -> 2-way on scatter-write AND frag-read
__device__ __forceinline__ int vv_idx(int d, int chunk) {
  return d * 64 + (((chunk ^ (d & 7) ^ ((d >> 3) & 7)) & 7) << 3);
}

// ---------------------------------------------------------------------------
__global__ __launch_bounds__(256) void f32_to_bf16(
    const float* __restrict__ in, unsigned short* __restrict__ out, int n4)
{
  const int i = blockIdx.x * 256 + threadIdx.x;
  if (i < n4) {
    const float4 v = ((const float4*)in)[i];
    const unsigned lo = (unsigned)f2bf(v.x) | ((unsigned)f2bf(v.y) << 16);
    const unsigned hi = (unsigned)f2bf(v.z) | ((unsigned)f2bf(v.w) << 16);
    ((uint2*)out)[i] = make_uint2(lo, hi);
  }
}

// ---------------------------------------------------------------------------
// C[m][n] = sum_k A[m][k]*B[n][k] + bias[n]; A,B bf16, bias fp32.
// bf16 MFMA 16x16x32, 128x128 tile, 4 waves, 4x4 frags/wave, BK=32.
// ---------------------------------------------------------------------------
template <bool OUT_BF16>
__global__ __launch_bounds__(256, 2) void gemm_bt_mfma(
    const unsigned short* __restrict__ A, const unsigned short* __restrict__ B,
    const float* __restrict__ bias, void* __restrict__ Cv,
    int M, int N, int K)
{
  __shared__ unsigned short As[128 * 32];
  __shared__ unsigned short Bs[128 * 32];

  const int tid  = threadIdx.x;
  const int lane = tid & 63;
  const int wv   = tid >> 6;
  const int wr   = wv >> 1, wc = wv & 1;
  const int l15  = lane & 15, g = lane >> 4;
  const int bn = blockIdx.x, bm = blockIdx.y;

  const int srow = tid >> 1;
  const int sh   = tid & 1;

  f32x4 acc[4][4];
#pragma unroll
  for (int i = 0; i < 4; ++i)
#pragma unroll
    for (int j = 0; j < 4; ++j) acc[i][j] = (f32x4){0.f, 0.f, 0.f, 0.f};

  for (int k0 = 0; k0 < K; k0 += 32) {
    __syncthreads();
    {
      const unsigned short* sa = A + (size_t)(bm * 128 + srow) * K + k0 + sh * 16;
      const unsigned short* sb = B + (size_t)(bn * 128 + srow) * K + k0 + sh * 16;
      const short8_t a0 = *(const short8_t*)(sa);
      const short8_t a1 = *(const short8_t*)(sa + 8);
      const short8_t b0 = *(const short8_t*)(sb);
      const short8_t b1 = *(const short8_t*)(sb + 8);
      *(short8_t*)&As[gemm_idx(srow, sh * 2 + 0)] = a0;
      *(short8_t*)&As[gemm_idx(srow, sh * 2 + 1)] = a1;
      *(short8_t*)&Bs[gemm_idx(srow, sh * 2 + 0)] = b0;
      *(short8_t*)&Bs[gemm_idx(srow, sh * 2 + 1)] = b1;
    }
    __syncthreads();

    short8_t af[4], bf[4];
#pragma unroll
    for (int i = 0; i < 4; ++i)
      af[i] = *(const short8_t*)&As[gemm_idx(wr * 64 + i * 16 + l15, g)];
#pragma unroll
    for (int j = 0; j < 4; ++j)
      bf[j] = *(const short8_t*)&Bs[gemm_idx(wc * 64 + j * 16 + l15, g)];
#pragma unroll
    for (int i = 0; i < 4; ++i)
#pragma unroll
      for (int j = 0; j < 4; ++j)
        acc[i][j] = __builtin_amdgcn_mfma_f32_16x16x32_bf16(af[i], bf[j], acc[i][j], 0, 0, 0);
  }

#pragma unroll
  for (int j = 0; j < 4; ++j) {
    const int col = bn * 128 + wc * 64 + j * 16 + l15;
    const float bj = bias[col];
#pragma unroll
    for (int i = 0; i < 4; ++i) {
#pragma unroll
      for (int r = 0; r < 4; ++r) {
        const int row = bm * 128 + wr * 64 + i * 16 + g * 4 + r;
        const float v = acc[i][j][r] + bj;
        if (OUT_BF16) ((unsigned short*)Cv)[(size_t)row * N + col] = f2bf(v);
        else          ((float*)Cv)[(size_t)row * N + col] = v;
      }
    }
  }
}

// ---------------------------------------------------------------------------
// Causal flash attention, bf16 MFMA 16x16x32.
// Block = 256 thr / 4 waves = 64 q-rows (16 per wave). KV tile = 64.
// K row-major swizzled; V^T swizzled; reg-prefetch of next KV tile;
// frag-level causal skip; defer-max (thr=8).
// grid: (32 zigzag-qt, NHEAD, BDIM).
// ---------------------------------------------------------------------------
__global__ __launch_bounds__(256, 4) void attn_mfma(
    const unsigned short* __restrict__ qkv, unsigned short* __restrict__ yb)
{
  __shared__ unsigned short Ks[64 * 64];
  __shared__ unsigned short Vt[64 * 64];
  __shared__ unsigned short Ps[4 * 16 * 72];

  const int tid  = threadIdx.x;
  const int lane = tid & 63;
  const int wv   = tid >> 6;
  const int l15  = lane & 15, g = lane >> 4;
  const int x = blockIdx.x, h = blockIdx.y, b = blockIdx.z;
  // zigzag: consecutive blocks pair heavy+light diagonals
  const int qt  = (x & 1) ? (31 - (x >> 1)) : (x >> 1);
  const int wq0 = qt * 64 + wv * 16;      // wave's first q row
  const int q_hi = wq0 + 15;

  const unsigned short* kbase = qkv + (size_t)(b * TSEQ) * C3 + CDIM + h * HDIM;
  const unsigned short* vbase = kbase + CDIM;

  // Q fragments (A-layout: row=l15, k=g*8+j), kk in {0,1}
  short8_t qf[2];
#pragma unroll
  for (int kk = 0; kk < 2; ++kk)
    qf[kk] = *(const short8_t*)(qkv +
        (size_t)(b * TSEQ + wq0 + l15) * C3 + h * HDIM + kk * 32 + g * 8);

  f32x4 O[4];
#pragma unroll
  for (int n = 0; n < 4; ++n) O[n] = (f32x4){0.f, 0.f, 0.f, 0.f};
  float Mr[4], Lr[4];
#pragma unroll
  for (int r = 0; r < 4; ++r) { Mr[r] = -3.0e38f; Lr[r] = 0.f; }

  unsigned short* Pw = &Ps[wv * 16 * 72];
  const int ntiles = qt + 1;

  // staging slots: row skv, 2 chunks starting at sa
  const int skv = tid >> 2;
  const int sa  = (tid & 3) * 2;
  const unsigned short* kptr = kbase + (size_t)skv * C3 + sa * 8;
  const unsigned short* vptr = vbase + (size_t)skv * C3 + sa * 8;
  short8_t pk0 = *(const short8_t*)(kptr);
  short8_t pk1 = *(const short8_t*)(kptr + 8);
  short8_t pv0 = *(const short8_t*)(vptr);
  short8_t pv1 = *(const short8_t*)(vptr + 8);

  for (int t = 0; t < ntiles; ++t) {
    __syncthreads();
    *(short8_t*)&Ks[kk_idx(skv, sa + 0)] = pk0;
    *(short8_t*)&Ks[kk_idx(skv, sa + 1)] = pk1;
    {
      const unsigned short* e0 = (const unsigned short*)&pv0;
      const unsigned short* e1 = (const unsigned short*)&pv1;
      const int vc = skv >> 3, ve = skv & 7;
#pragma unroll
      for (int j = 0; j < 8; ++j) {
        Vt[vv_idx(sa * 8 + j, vc) + ve]     = e0[j];
        Vt[vv_idx(sa * 8 + 8 + j, vc) + ve] = e1[j];
      }
    }
    __syncthreads();
    if (t + 1 < ntiles) {     // issue next tile's loads before compute
      kptr += (size_t)64 * C3; vptr += (size_t)64 * C3;
      pk0 = *(const short8_t*)(kptr); pk1 = *(const short8_t*)(kptr + 8);
      pv0 = *(const short8_t*)(vptr); pv1 = *(const short8_t*)(vptr + 8);
    }
    const int kv0 = t * 64;
    if (kv0 > q_hi) continue;             // wave-uniform; loads already issued
    const int nlim = (q_hi - kv0) >> 4;   // frags with any unmasked element

    // S = Q K^T  (D-layout: row(q)=g*4+r, col(kv)=l15)
    f32x4 s[4];
#pragma unroll
    for (int n = 0; n < 4; ++n) {
      s[n] = (f32x4){0.f, 0.f, 0.f, 0.f};
      if (n <= nlim) {
#pragma unroll
        for (int kk = 0; kk < 2; ++kk) {
          const short8_t kf = *(const short8_t*)&Ks[kk_idx(n * 16 + l15, kk * 4 + g)];
          s[n] = __builtin_amdgcn_mfma_f32_16x16x32_bf16(qf[kk], kf, s[n], 0, 0, 0);
        }
      }
    }
    // scale + causal mask
#pragma unroll
    for (int n = 0; n < 4; ++n) {
      if (n > nlim) {
#pragma unroll
        for (int r = 0; r < 4; ++r) s[n][r] = -3.0e38f;
      } else {
        const bool needmask = (kv0 + n * 16 + 15 > wq0);
#pragma unroll
        for (int r = 0; r < 4; ++r) {
          float v = s[n][r] * 0.125f;
          if (needmask && (kv0 + n * 16 + l15 > wq0 + g * 4 + r)) v = -3.0e38f;
          s[n][r] = v;
        }
      }
    }

    // online softmax over kv (regs n + lanes l15); rows are (g,r)-local
    float mt[4];
#pragma unroll
    for (int r = 0; r < 4; ++r)
      mt[r] = fmaxf(fmaxf(s[0][r], s[1][r]), fmaxf(s[2][r], s[3][r]));
#pragma unroll
    for (int off = 1; off < 16; off <<= 1)
#pragma unroll
      for (int r = 0; r < 4; ++r) mt[r] = fmaxf(mt[r], __shfl_xor(mt[r], off));

    bool grow = false;
#pragma unroll
    for (int r = 0; r < 4; ++r) grow = grow || (mt[r] > Mr[r] + 8.0f);
    if (__any(grow)) {                    // defer-max: rescale only on growth
#pragma unroll
      for (int r = 0; r < 4; ++r) {
        const float nm = fmaxf(Mr[r], mt[r]);
        const float al = __expf(Mr[r] - nm);
        Lr[r] *= al;
#pragma unroll
        for (int n = 0; n < 4; ++n) O[n][r] *= al;
        Mr[r] = nm;
      }
    }

    float rs[4] = {0.f, 0.f, 0.f, 0.f};
#pragma unroll
    for (int n = 0; n < 4; ++n)
#pragma unroll
      for (int r = 0; r < 4; ++r) {
        const float p = __expf(s[n][r] - Mr[r]);
        s[n][r] = p;
        rs[r] += p;
      }
#pragma unroll
    for (int off = 1; off < 16; off <<= 1)
#pragma unroll
      for (int r = 0; r < 4; ++r) rs[r] += __shfl_xor(rs[r], off);
#pragma unroll
    for (int r = 0; r < 4; ++r) Lr[r] += rs[r];

    // P (bf16) -> per-wave LDS [16 q][72]
#pragma unroll
    for (int n = 0; n < 4; ++n)
#pragma unroll
      for (int r = 0; r < 4; ++r)
        Pw[(g * 4 + r) * 72 + n * 16 + l15] = f2bf(s[n][r]);

    // PV: A = P (row=l15, k=kk*32+g*8+j), B = V^T (col(d)=l15)
#pragma unroll
    for (int kk = 0; kk < 2; ++kk) {
      const short8_t pf = *(const short8_t*)&Pw[l15 * 72 + kk * 32 + g * 8];
#pragma unroll
      for (int n = 0; n < 4; ++n) {
        const short8_t vf = *(const short8_t*)&Vt[vv_idx(n * 16 + l15, kk * 4 + g)];
        O[n] = __builtin_amdgcn_mfma_f32_16x16x32_bf16(pf, vf, O[n], 0, 0, 0);
      }
    }
  }

  // epilogue
  float inv[4];
#pragma unroll
  for (int r = 0; r < 4; ++r) inv[r] = 1.0f / Lr[r];
#pragma unroll
  for (int n = 0; n < 4; ++n)
#pragma unroll
    for (int r = 0; r < 4; ++r) {
      const size_t row = (size_t)(b * TSEQ + wq0 + g * 4 + r);
      yb[row * CDIM + h * HDIM + n * 16 + l15] = f2bf(O[n][r] * inv[r]);
    }
}

// ---------------------------------------------------------------------------
extern "C" void kernel_launch(void* const* d_in, const int* in_sizes, int n_in,
                              void* d_out, int out_size, void* d_ws, size_t ws_size,
                              hipStream_t stream)
{
  const float* x     = (const float*)d_in[0];   // [B,T,C] fp32
  const float* Wqkv  = (const float*)d_in[1];   // [3C,C]  fp32
  const float* bqkv  = (const float*)d_in[2];   // [3C]
  const float* Wproj = (const float*)d_in[3];   // [C,C]
  const float* bproj = (const float*)d_in[4];   // [C]
  float* out = (float*)d_out;                   // [B,T,C] fp32

  const int M = BDIM * TSEQ;                    // 4096
  unsigned short* qkv = (unsigned short*)d_ws;          // M x 3C
  unsigned short* yb  = qkv + (size_t)M * C3;           // M x C
  unsigned short* xb  = yb  + (size_t)M * CDIM;         // M x C
  unsigned short* wqb = xb  + (size_t)M * CDIM;         // 3C x C
  unsigned short* wpb = wqb + (size_t)C3 * CDIM;        // C x C

  // 0) fp32 -> bf16 pre-conversion (RNE, same numerics as inline convert)
  f32_to_bf16<<<(M * CDIM / 4 + 255) / 256, 256, 0, stream>>>(x, xb, M * CDIM / 4);
  f32_to_bf16<<<(C3 * CDIM / 4 + 255) / 256, 256, 0, stream>>>(Wqkv, wqb, C3 * CDIM / 4);
  f32_to_bf16<<<(CDIM * CDIM / 4 + 255) / 256, 256, 0, stream>>>(Wproj, wpb, CDIM * CDIM / 4);

  // 1) qkv = bf16(x @ Wqkv^T + bqkv)
  gemm_bt_mfma<true><<<dim3(C3 / 128, M / 128), 256, 0, stream>>>(
      xb, wqb, bqkv, (void*)qkv, M, C3, CDIM);

  // 2) causal attention -> yb (bf16)
  attn_mfma<<<dim3(TSEQ / 64, NHEAD, BDIM), 256, 0, stream>>>(qkv, yb);

  // 3) out = yb @ Wproj^T + bproj (fp32 out)
  gemm_bt_mfma<false><<<dim3(CDIM / 128, M / 128), 256, 0, stream>>>(
      yb, wpb, bproj, (void*)out, M, CDIM, CDIM);
}

// Round 4
// 156.934 us; speedup vs baseline: 14.0096x; 1.2661x over previous
//
#include <hip/hip_runtime.h>
#include <cstdint>

#define BDIM  2
#define TSEQ  2048
#define CDIM  1024
#define NHEAD 16
#define HDIM  64
#define C3    3072

typedef __attribute__((ext_vector_type(8))) short short8_t;
typedef __attribute__((ext_vector_type(4))) float f32x4;

static __device__ __forceinline__ unsigned short f2bf(float f) {
  union { float f; unsigned u; } v; v.f = f;
  unsigned r = v.u + 0x7FFFu + ((v.u >> 16) & 1u);   // RNE
  return (unsigned short)(r >> 16);
}

// GEMM tiles: [128 rows][32 k] bf16, 16B chunks 0..3, chunk ^= (row>>1)&3
__device__ __forceinline__ int gemm_idx(int row, int chunk) {
  return row * 32 + (((chunk ^ ((row >> 1) & 3)) & 3) << 3);
}
// attn K tile: [64 kv][64 d] bf16, chunks 0..7 (d>>3), chunk ^= kv&7
__device__ __forceinline__ int kk_idx(int kv, int chunk) {
  return kv * 64 + (((chunk ^ (kv & 7)) & 7) << 3);
}
// attn V^T tile: [64 d][64 kv] bf16, chunks 0..7 (kv>>3),
// chunk ^= (d&7) ^ ((d>>3)&7)
__device__ __forceinline__ int vv_idx(int d, int chunk) {
  return d * 64 + (((chunk ^ (d & 7) ^ ((d >> 3) & 7)) & 7) << 3);
}

// ---------------------------------------------------------------------------
__global__ __launch_bounds__(256) void f32_to_bf16(
    const float* __restrict__ in, unsigned short* __restrict__ out, int n4)
{
  const int i = blockIdx.x * 256 + threadIdx.x;
  if (i < n4) {
    const float4 v = ((const float4*)in)[i];
    const unsigned lo = (unsigned)f2bf(v.x) | ((unsigned)f2bf(v.y) << 16);
    const unsigned hi = (unsigned)f2bf(v.z) | ((unsigned)f2bf(v.w) << 16);
    ((uint2*)out)[i] = make_uint2(lo, hi);
  }
}

// ---------------------------------------------------------------------------
// C[m][n] = sum_k A[m][k]*B[n][k] + bias[n]; A,B bf16, bias fp32.
// bf16 MFMA 16x16x32, 128x128 tile, 4 waves, 4x4 frags/wave, BK=32.
// ---------------------------------------------------------------------------
template <bool OUT_BF16>
__global__ __launch_bounds__(256, 2) void gemm_bt_mfma(
    const unsigned short* __restrict__ A, const unsigned short* __restrict__ B,
    const float* __restrict__ bias, void* __restrict__ Cv,
    int M, int N, int K)
{
  __shared__ unsigned short As[128 * 32];
  __shared__ unsigned short Bs[128 * 32];

  const int tid  = threadIdx.x;
  const int lane = tid & 63;
  const int wv   = tid >> 6;
  const int wr   = wv >> 1, wc = wv & 1;
  const int l15  = lane & 15, g = lane >> 4;
  const int bn = blockIdx.x, bm = blockIdx.y;

  const int srow = tid >> 1;
  const int sh   = tid & 1;

  f32x4 acc[4][4];
#pragma unroll
  for (int i = 0; i < 4; ++i)
#pragma unroll
    for (int j = 0; j < 4; ++j) acc[i][j] = (f32x4){0.f, 0.f, 0.f, 0.f};

  for (int k0 = 0; k0 < K; k0 += 32) {
    __syncthreads();
    {
      const unsigned short* sa = A + (size_t)(bm * 128 + srow) * K + k0 + sh * 16;
      const unsigned short* sb = B + (size_t)(bn * 128 + srow) * K + k0 + sh * 16;
      const short8_t a0 = *(const short8_t*)(sa);
      const short8_t a1 = *(const short8_t*)(sa + 8);
      const short8_t b0 = *(const short8_t*)(sb);
      const short8_t b1 = *(const short8_t*)(sb + 8);
      *(short8_t*)&As[gemm_idx(srow, sh * 2 + 0)] = a0;
      *(short8_t*)&As[gemm_idx(srow, sh * 2 + 1)] = a1;
      *(short8_t*)&Bs[gemm_idx(srow, sh * 2 + 0)] = b0;
      *(short8_t*)&Bs[gemm_idx(srow, sh * 2 + 1)] = b1;
    }
    __syncthreads();

    short8_t af[4], bf[4];
#pragma unroll
    for (int i = 0; i < 4; ++i)
      af[i] = *(const short8_t*)&As[gemm_idx(wr * 64 + i * 16 + l15, g)];
#pragma unroll
    for (int j = 0; j < 4; ++j)
      bf[j] = *(const short8_t*)&Bs[gemm_idx(wc * 64 + j * 16 + l15, g)];
#pragma unroll
    for (int i = 0; i < 4; ++i)
#pragma unroll
      for (int j = 0; j < 4; ++j)
        acc[i][j] = __builtin_amdgcn_mfma_f32_16x16x32_bf16(af[i], bf[j], acc[i][j], 0, 0, 0);
  }

#pragma unroll
  for (int j = 0; j < 4; ++j) {
    const int col = bn * 128 + wc * 64 + j * 16 + l15;
    const float bj = bias[col];
#pragma unroll
    for (int i = 0; i < 4; ++i) {
#pragma unroll
      for (int r = 0; r < 4; ++r) {
        const int row = bm * 128 + wr * 64 + i * 16 + g * 4 + r;
        const float v = acc[i][j][r] + bj;
        if (OUT_BF16) ((unsigned short*)Cv)[(size_t)row * N + col] = f2bf(v);
        else          ((float*)Cv)[(size_t)row * N + col] = v;
      }
    }
  }
}

// ---------------------------------------------------------------------------
// Causal flash attention, bf16 MFMA 16x16x32.
// Block = 256 thr / 4 waves. Each block processes TWO q-tiles of 64 rows:
// qt=x (x+1 kv tiles) then qt=31-x (32-x tiles) -> 33 tiles for EVERY block
// (perfect balance, no dispatch-dependent tail). Wave owns 16 q-rows.
// K row-major swizzled; V^T swizzled (packed-pair b32 writes); register
// prefetch of next KV tile; frag-level causal skip + guarded softmax;
// defer-max (thr=8).  grid: (16, NHEAD, BDIM).
// ---------------------------------------------------------------------------
__global__ __launch_bounds__(256, 2) void attn_mfma(
    const unsigned short* __restrict__ qkv, unsigned short* __restrict__ yb)
{
  __shared__ unsigned short Ks[64 * 64];
  __shared__ unsigned short Vt[64 * 64];
  __shared__ unsigned short Ps[4 * 16 * 72];

  const int tid  = threadIdx.x;
  const int lane = tid & 63;
  const int wv   = tid >> 6;
  const int l15  = lane & 15, g = lane >> 4;
  const int x = blockIdx.x, h = blockIdx.y, b = blockIdx.z;

  const unsigned short* kbase = qkv + (size_t)(b * TSEQ) * C3 + CDIM + h * HDIM;
  const unsigned short* vbase = kbase + CDIM;
  unsigned short* Pw = &Ps[wv * 16 * 72];

  // ---- loop-invariant staging addresses ----
  // K: thread -> (row skv, chunks sa, sa+1)
  const int skv = tid >> 2;
  const int sa  = (tid & 3) * 2;
  unsigned short* kw0 = &Ks[kk_idx(skv, sa + 0)];
  unsigned short* kw1 = &Ks[kk_idx(skv, sa + 1)];
  // V: thread -> (rows 2*vs, 2*vs+1, d-chunk va); packed b32 writes
  const int vs = tid >> 3;            // 0..31
  const int va = tid & 7;             // 0..7
  unsigned* vw[8];
#pragma unroll
  for (int j = 0; j < 8; ++j)
    vw[j] = (unsigned*)&Vt[vv_idx(va * 8 + j, vs >> 2) + ((2 * vs) & 7)];

  for (int ph = 0; ph < 2; ++ph) {
    const int qt   = ph ? (31 - x) : x;
    const int wq0  = qt * 64 + wv * 16;
    const int q_hi = wq0 + 15;
    const int ntiles = qt + 1;

    // Q fragments (A-layout: row=l15, k=g*8+j)
    short8_t qf[2];
#pragma unroll
    for (int kk = 0; kk < 2; ++kk)
      qf[kk] = *(const short8_t*)(qkv +
          (size_t)(b * TSEQ + wq0 + l15) * C3 + h * HDIM + kk * 32 + g * 8);

    f32x4 O[4];
#pragma unroll
    for (int n = 0; n < 4; ++n) O[n] = (f32x4){0.f, 0.f, 0.f, 0.f};
    float Mr[4], Lr[4];
#pragma unroll
    for (int r = 0; r < 4; ++r) { Mr[r] = -3.0e38f; Lr[r] = 0.f; }

    // prefetch tile 0 of this phase
    const unsigned short* kptr  = kbase + (size_t)skv * C3 + sa * 8;
    const unsigned short* vptr0 = vbase + (size_t)(2 * vs) * C3 + va * 8;
    const unsigned short* vptr1 = vptr0 + C3;
    short8_t pk0 = *(const short8_t*)(kptr);
    short8_t pk1 = *(const short8_t*)(kptr + 8);
    short8_t pv0 = *(const short8_t*)(vptr0);
    short8_t pv1 = *(const short8_t*)(vptr1);

    for (int t = 0; t < ntiles; ++t) {
      __syncthreads();
      *(short8_t*)kw0 = pk0;
      *(short8_t*)kw1 = pk1;
      {
        const unsigned short* e0 = (const unsigned short*)&pv0;
        const unsigned short* e1 = (const unsigned short*)&pv1;
#pragma unroll
        for (int j = 0; j < 8; ++j)
          *vw[j] = (unsigned)e0[j] | ((unsigned)e1[j] << 16);
      }
      __syncthreads();
      if (t + 1 < ntiles) {   // issue next tile's loads before compute
        kptr  += (size_t)64 * C3;
        vptr0 += (size_t)64 * C3;
        vptr1 += (size_t)64 * C3;
        pk0 = *(const short8_t*)(kptr); pk1 = *(const short8_t*)(kptr + 8);
        pv0 = *(const short8_t*)(vptr0); pv1 = *(const short8_t*)(vptr1);
      }
      const int kv0 = t * 64;
      if (kv0 > q_hi) continue;           // wave-uniform (last tile of phase)
      const int nlim = (q_hi - kv0) >> 4; // highest frag with unmasked cols

      // S = Q K^T (D-layout: row(q)=g*4+r, col(kv)=l15)
      f32x4 s[4];
#pragma unroll
      for (int n = 0; n < 4; ++n) s[n] = (f32x4){0.f, 0.f, 0.f, 0.f};
#pragma unroll
      for (int n = 0; n < 4; ++n) {
        if (n <= nlim) {
#pragma unroll
          for (int kk = 0; kk < 2; ++kk) {
            const short8_t kf = *(const short8_t*)&Ks[kk_idx(n * 16 + l15, kk * 4 + g)];
            s[n] = __builtin_amdgcn_mfma_f32_16x16x32_bf16(qf[kk], kf, s[n], 0, 0, 0);
          }
        }
      }

      // scale + causal mask + row max (guarded to valid frags)
      float mt[4] = {-3.0e38f, -3.0e38f, -3.0e38f, -3.0e38f};
#pragma unroll
      for (int n = 0; n < 4; ++n) {
        if (n <= nlim) {
          const bool needmask = (kv0 + n * 16 + 15 > wq0);
#pragma unroll
          for (int r = 0; r < 4; ++r) {
            float v = s[n][r] * 0.125f;
            if (needmask && (kv0 + n * 16 + l15 > wq0 + g * 4 + r)) v = -3.0e38f;
            s[n][r] = v;
            mt[r] = fmaxf(mt[r], v);
          }
        }
      }
#pragma unroll
      for (int off = 1; off < 16; off <<= 1)
#pragma unroll
        for (int r = 0; r < 4; ++r) mt[r] = fmaxf(mt[r], __shfl_xor(mt[r], off));

      bool grow = false;
#pragma unroll
      for (int r = 0; r < 4; ++r) grow = grow || (mt[r] > Mr[r] + 8.0f);
      if (__any(grow)) {                  // defer-max
#pragma unroll
        for (int r = 0; r < 4; ++r) {
          const float nm = fmaxf(Mr[r], mt[r]);
          const float al = __expf(Mr[r] - nm);
          Lr[r] *= al;
#pragma unroll
          for (int n = 0; n < 4; ++n) O[n][r] *= al;
          Mr[r] = nm;
        }
      }

      float rs[4] = {0.f, 0.f, 0.f, 0.f};
#pragma unroll
      for (int n = 0; n < 4; ++n) {
        if (n <= nlim) {
#pragma unroll
          for (int r = 0; r < 4; ++r) {
            const float p = __expf(s[n][r] - Mr[r]);
            s[n][r] = p;
            rs[r] += p;
          }
        }
        // n > nlim: s[n] stays 0 -> P columns are zero (PV-safe)
      }
#pragma unroll
      for (int off = 1; off < 16; off <<= 1)
#pragma unroll
        for (int r = 0; r < 4; ++r) rs[r] += __shfl_xor(rs[r], off);
#pragma unroll
      for (int r = 0; r < 4; ++r) Lr[r] += rs[r];

      // P (bf16) -> per-wave LDS [16 q][72]
#pragma unroll
      for (int n = 0; n < 4; ++n)
#pragma unroll
        for (int r = 0; r < 4; ++r)
          Pw[(g * 4 + r) * 72 + n * 16 + l15] = f2bf(s[n][r]);

      // PV: A = P (row=l15, k=kk*32+g*8+j), B = V^T (col(d)=l15)
#pragma unroll
      for (int kk = 0; kk < 2; ++kk) {
        const short8_t pf = *(const short8_t*)&Pw[l15 * 72 + kk * 32 + g * 8];
#pragma unroll
        for (int n = 0; n < 4; ++n) {
          const short8_t vf = *(const short8_t*)&Vt[vv_idx(n * 16 + l15, kk * 4 + g)];
          O[n] = __builtin_amdgcn_mfma_f32_16x16x32_bf16(pf, vf, O[n], 0, 0, 0);
        }
      }
    }

    // epilogue for this q-tile
    float inv[4];
#pragma unroll
    for (int r = 0; r < 4; ++r) inv[r] = 1.0f / Lr[r];
#pragma unroll
    for (int n = 0; n < 4; ++n)
#pragma unroll
      for (int r = 0; r < 4; ++r) {
        const size_t row = (size_t)(b * TSEQ + wq0 + g * 4 + r);
        yb[row * CDIM + h * HDIM + n * 16 + l15] = f2bf(O[n][r] * inv[r]);
      }
  }
}

// ---------------------------------------------------------------------------
extern "C" void kernel_launch(void* const* d_in, const int* in_sizes, int n_in,
                              void* d_out, int out_size, void* d_ws, size_t ws_size,
                              hipStream_t stream)
{
  const float* x     = (const float*)d_in[0];   // [B,T,C] fp32
  const float* Wqkv  = (const float*)d_in[1];   // [3C,C]  fp32
  const float* bqkv  = (const float*)d_in[2];   // [3C]
  const float* Wproj = (const float*)d_in[3];   // [C,C]
  const float* bproj = (const float*)d_in[4];   // [C]
  float* out = (float*)d_out;                   // [B,T,C] fp32

  const int M = BDIM * TSEQ;                    // 4096
  unsigned short* qkv = (unsigned short*)d_ws;          // M x 3C
  unsigned short* yb  = qkv + (size_t)M * C3;           // M x C
  unsigned short* xb  = yb  + (size_t)M * CDIM;         // M x C
  unsigned short* wqb = xb  + (size_t)M * CDIM;         // 3C x C
  unsigned short* wpb = wqb + (size_t)C3 * CDIM;        // C x C

  // 0) fp32 -> bf16 pre-conversion (RNE)
  f32_to_bf16<<<(M * CDIM / 4 + 255) / 256, 256, 0, stream>>>(x, xb, M * CDIM / 4);
  f32_to_bf16<<<(C3 * CDIM / 4 + 255) / 256, 256, 0, stream>>>(Wqkv, wqb, C3 * CDIM / 4);
  f32_to_bf16<<<(CDIM * CDIM / 4 + 255) / 256, 256, 0, stream>>>(Wproj, wpb, CDIM * CDIM / 4);

  // 1) qkv = bf16(x @ Wqkv^T + bqkv)
  gemm_bt_mfma<true><<<dim3(C3 / 128, M / 128), 256, 0, stream>>>(
      xb, wqb, bqkv, (void*)qkv, M, C3, CDIM);

  // 2) causal attention -> yb (bf16)
  attn_mfma<<<dim3(16, NHEAD, BDIM), 256, 0, stream>>>(qkv, yb);

  // 3) out = yb @ Wproj^T + bproj (fp32 out)
  gemm_bt_mfma<false><<<dim3(CDIM / 128, M / 128), 256, 0, stream>>>(
      yb, wpb, bproj, (void*)out, M, CDIM, CDIM);
}

// Round 5
// 131.985 us; speedup vs baseline: 16.6579x; 1.1890x over previous
//
#include <hip/hip_runtime.h>
#include <cstdint>

#define BDIM  2
#define TSEQ  2048
#define CDIM  1024
#define NHEAD 16
#define HDIM  64
#define C3    3072

typedef __attribute__((ext_vector_type(8))) short short8_t;
typedef __attribute__((ext_vector_type(4))) float f32x4;

static __device__ __forceinline__ unsigned short f2bf(float f) {
  union { float f; unsigned u; } v; v.f = f;
  unsigned r = v.u + 0x7FFFu + ((v.u >> 16) & 1u);   // RNE
  return (unsigned short)(r >> 16);
}
// pack 2 f32 -> 2 bf16 in one u32 (v_cvt_pk_bf16_f32, RNE)
static __device__ __forceinline__ unsigned cvtpk_bf16(float lo, float hi) {
  unsigned r;
  asm("v_cvt_pk_bf16_f32 %0, %1, %2" : "=v"(r) : "v"(lo), "v"(hi));
  return r;
}

// GEMM tiles: [128 rows][32 k] bf16, 16B chunks 0..3, chunk ^= (row>>1)&3
__device__ __forceinline__ int gemm_idx(int row, int chunk) {
  return row * 32 + (((chunk ^ ((row >> 1) & 3)) & 3) << 3);
}
// attn K tile: [64 kv][64 d] bf16, chunks 0..7 (d>>3), chunk ^= kv&7
__device__ __forceinline__ int kk_idx(int kv, int chunk) {
  return kv * 64 + (((chunk ^ (kv & 7)) & 7) << 3);
}
// attn V^T tile: [64 d][64 kv] bf16, chunks 0..7 (kv>>3),
// chunk ^= (d&7) ^ ((d>>3)&7)
__device__ __forceinline__ int vv_idx(int d, int chunk) {
  return d * 64 + (((chunk ^ (d & 7) ^ ((d >> 3) & 7)) & 7) << 3);
}

// ---------------------------------------------------------------------------
__global__ __launch_bounds__(256) void f32_to_bf16(
    const float* __restrict__ in, unsigned short* __restrict__ out, int n4)
{
  const int i = blockIdx.x * 256 + threadIdx.x;
  if (i < n4) {
    const float4 v = ((const float4*)in)[i];
    const unsigned lo = (unsigned)f2bf(v.x) | ((unsigned)f2bf(v.y) << 16);
    const unsigned hi = (unsigned)f2bf(v.z) | ((unsigned)f2bf(v.w) << 16);
    ((uint2*)out)[i] = make_uint2(lo, hi);
  }
}

// ---------------------------------------------------------------------------
// C[m][n] = sum_k A[m][k]*B[n][k] + bias[n]; A,B bf16, bias fp32.
// bf16 MFMA 16x16x32, 128x128 tile, 4 waves, 4x4 frags/wave, BK=32.
// ---------------------------------------------------------------------------
template <bool OUT_BF16>
__global__ __launch_bounds__(256, 2) void gemm_bt_mfma(
    const unsigned short* __restrict__ A, const unsigned short* __restrict__ B,
    const float* __restrict__ bias, void* __restrict__ Cv,
    int M, int N, int K)
{
  __shared__ unsigned short As[128 * 32];
  __shared__ unsigned short Bs[128 * 32];

  const int tid  = threadIdx.x;
  const int lane = tid & 63;
  const int wv   = tid >> 6;
  const int wr   = wv >> 1, wc = wv & 1;
  const int l15  = lane & 15, g = lane >> 4;
  const int bn = blockIdx.x, bm = blockIdx.y;

  const int srow = tid >> 1;
  const int sh   = tid & 1;

  f32x4 acc[4][4];
#pragma unroll
  for (int i = 0; i < 4; ++i)
#pragma unroll
    for (int j = 0; j < 4; ++j) acc[i][j] = (f32x4){0.f, 0.f, 0.f, 0.f};

  for (int k0 = 0; k0 < K; k0 += 32) {
    __syncthreads();
    {
      const unsigned short* sa = A + (size_t)(bm * 128 + srow) * K + k0 + sh * 16;
      const unsigned short* sb = B + (size_t)(bn * 128 + srow) * K + k0 + sh * 16;
      const short8_t a0 = *(const short8_t*)(sa);
      const short8_t a1 = *(const short8_t*)(sa + 8);
      const short8_t b0 = *(const short8_t*)(sb);
      const short8_t b1 = *(const short8_t*)(sb + 8);
      *(short8_t*)&As[gemm_idx(srow, sh * 2 + 0)] = a0;
      *(short8_t*)&As[gemm_idx(srow, sh * 2 + 1)] = a1;
      *(short8_t*)&Bs[gemm_idx(srow, sh * 2 + 0)] = b0;
      *(short8_t*)&Bs[gemm_idx(srow, sh * 2 + 1)] = b1;
    }
    __syncthreads();

    short8_t af[4], bf[4];
#pragma unroll
    for (int i = 0; i < 4; ++i)
      af[i] = *(const short8_t*)&As[gemm_idx(wr * 64 + i * 16 + l15, g)];
#pragma unroll
    for (int j = 0; j < 4; ++j)
      bf[j] = *(const short8_t*)&Bs[gemm_idx(wc * 64 + j * 16 + l15, g)];
#pragma unroll
    for (int i = 0; i < 4; ++i)
#pragma unroll
      for (int j = 0; j < 4; ++j)
        acc[i][j] = __builtin_amdgcn_mfma_f32_16x16x32_bf16(af[i], bf[j], acc[i][j], 0, 0, 0);
  }

#pragma unroll
  for (int j = 0; j < 4; ++j) {
    const int col = bn * 128 + wc * 64 + j * 16 + l15;
    const float bj = bias[col];
#pragma unroll
    for (int i = 0; i < 4; ++i) {
#pragma unroll
      for (int r = 0; r < 4; ++r) {
        const int row = bm * 128 + wr * 64 + i * 16 + g * 4 + r;
        const float v = acc[i][j][r] + bj;
        if (OUT_BF16) ((unsigned short*)Cv)[(size_t)row * N + col] = f2bf(v);
        else          ((float*)Cv)[(size_t)row * N + col] = v;
      }
    }
  }
}

// ---------------------------------------------------------------------------
// Causal flash attention, bf16 MFMA 16x16x32, SWAPPED QK^T (S^T = K·Q^T):
// each lane's S values all belong to q = lane&15 -> lane-local softmax
// (scalar m,l; 2 shuffles per reduce), packed b64 P writes via cvt_pk.
// Block = 4 waves; block does q-tiles x and 31-x (33 KV tiles, balanced).
// K/V LDS double-buffered (1 barrier/tile); register prefetch of next tile.
// grid: (16, NHEAD, BDIM).
// ---------------------------------------------------------------------------
__global__ __launch_bounds__(256, 2) void attn_mfma(
    const unsigned short* __restrict__ qkv, unsigned short* __restrict__ yb)
{
  __shared__ unsigned short Ks[2 * 64 * 64];
  __shared__ unsigned short Vt[2 * 64 * 64];
  __shared__ unsigned short Ps[4 * 16 * 72];

  const int tid  = threadIdx.x;
  const int lane = tid & 63;
  const int wv   = tid >> 6;
  const int l15  = lane & 15, g = lane >> 4;
  const int x = blockIdx.x, h = blockIdx.y, b = blockIdx.z;

  const unsigned short* kbase = qkv + (size_t)(b * TSEQ) * C3 + CDIM + h * HDIM;
  const unsigned short* vbase = kbase + CDIM;
  unsigned short* Pw = &Ps[wv * 16 * 72];

  const float SC2 = 0.18033688011112042f;   // log2(e)/8
  const float THR = 11.5415603f;            // 8*log2(e)

  // ---- loop-invariant staging offsets ----
  const int skv = tid >> 2;
  const int sa  = (tid & 3) * 2;
  const int kw0 = kk_idx(skv, sa + 0);
  const int kw1 = kk_idx(skv, sa + 1);
  const int vs = tid >> 3;            // 0..31 (kv pair)
  const int va = tid & 7;             // 0..7  (d chunk)
  int vwo[8];
#pragma unroll
  for (int j = 0; j < 8; ++j)
    vwo[j] = vv_idx(va * 8 + j, vs >> 2) + ((2 * vs) & 7);

  int tg = 0;   // global staged-tile parity (continuous across phases)

  for (int ph = 0; ph < 2; ++ph) {
    const int qt   = ph ? (31 - x) : x;
    const int wq0  = qt * 64 + wv * 16;
    const int q_hi = wq0 + 15;
    const int qg   = wq0 + l15;         // this lane's q row
    const int ntiles = qt + 1;

    // Q fragment (B-operand: col=q=l15, k=g*8+j)
    short8_t qf[2];
#pragma unroll
    for (int kk = 0; kk < 2; ++kk)
      qf[kk] = *(const short8_t*)(qkv +
          (size_t)(b * TSEQ + wq0 + l15) * C3 + h * HDIM + kk * 32 + g * 8);

    f32x4 O[4];
#pragma unroll
    for (int n = 0; n < 4; ++n) O[n] = (f32x4){0.f, 0.f, 0.f, 0.f};
    float Mr = -3.0e38f, Lr = 0.f;      // per-lane (q = l15)

    // prefetch tile 0 of this phase into registers
    const unsigned short* kptr  = kbase + (size_t)skv * C3 + sa * 8;
    const unsigned short* vptr0 = vbase + (size_t)(2 * vs) * C3 + va * 8;
    const unsigned short* vptr1 = vptr0 + C3;
    short8_t pk0 = *(const short8_t*)(kptr);
    short8_t pk1 = *(const short8_t*)(kptr + 8);
    short8_t pv0 = *(const short8_t*)(vptr0);
    short8_t pv1 = *(const short8_t*)(vptr1);

    for (int t = 0; t < ntiles; ++t) {
      unsigned short* Kc = &Ks[(tg & 1) * 4096];
      unsigned short* Vc = &Vt[(tg & 1) * 4096];
      tg++;
      Kc[0] = Kc[0];  // no-op keeps compiler from reordering? (harmless)
      *(short8_t*)&Kc[kw0] = pk0;
      *(short8_t*)&Kc[kw1] = pk1;
      {
        const unsigned short* e0 = (const unsigned short*)&pv0;
        const unsigned short* e1 = (const unsigned short*)&pv1;
#pragma unroll
        for (int j = 0; j < 8; ++j)
          *(unsigned*)&Vc[vwo[j]] = (unsigned)e0[j] | ((unsigned)e1[j] << 16);
      }
      __syncthreads();
      if (t + 1 < ntiles) {   // issue next tile's loads before compute
        kptr  += (size_t)64 * C3;
        vptr0 += (size_t)64 * C3;
        vptr1 += (size_t)64 * C3;
        pk0 = *(const short8_t*)(kptr); pk1 = *(const short8_t*)(kptr + 8);
        pv0 = *(const short8_t*)(vptr0); pv1 = *(const short8_t*)(vptr1);
      }
      const int kv0  = t * 64;
      const int nlim = (q_hi - kv0) >> 4;   // highest frag with unmasked cols

      // S^T = K Q^T  (D-layout: row(kv)=g*4+r, col(q)=l15)
      f32x4 s[4];
#pragma unroll
      for (int n = 0; n < 4; ++n) s[n] = (f32x4){0.f, 0.f, 0.f, 0.f};
#pragma unroll
      for (int n = 0; n < 4; ++n) {
        if (n <= nlim) {
#pragma unroll
          for (int kk = 0; kk < 2; ++kk) {
            const short8_t kf = *(const short8_t*)&Kc[kk_idx(n * 16 + l15, kk * 4 + g)];
            s[n] = __builtin_amdgcn_mfma_f32_16x16x32_bf16(kf, qf[kk], s[n], 0, 0, 0);
          }
        }
      }

      // scale (log2 domain) + causal mask + lane-local max
      float mt = -3.0e38f;
#pragma unroll
      for (int n = 0; n < 4; ++n) {
        if (n <= nlim) {
          const int kvb = kv0 + n * 16 + g * 4;
          const bool needmask = (kv0 + n * 16 + 15 > wq0);
#pragma unroll
          for (int r = 0; r < 4; ++r) {
            float v = s[n][r] * SC2;
            if (needmask && (kvb + r > qg)) v = -3.0e38f;
            s[n][r] = v;
            mt = fmaxf(mt, v);
          }
        }
      }
      mt = fmaxf(mt, __shfl_xor(mt, 16));
      mt = fmaxf(mt, __shfl_xor(mt, 32));

      if (__any(mt > Mr + THR)) {           // defer-max rescale
        const float nm = fmaxf(Mr, mt);
        const float al = __builtin_amdgcn_exp2f(Mr - nm);
        Lr *= al;
        Mr = nm;
        float alq[4];
#pragma unroll
        for (int r = 0; r < 4; ++r) alq[r] = __shfl(al, (g << 2) + r);
#pragma unroll
        for (int n = 0; n < 4; ++n)
#pragma unroll
          for (int r = 0; r < 4; ++r) O[n][r] *= alq[r];
      }

      float rs = 0.f;
#pragma unroll
      for (int n = 0; n < 4; ++n) {
        if (n <= nlim) {
#pragma unroll
          for (int r = 0; r < 4; ++r) {
            const float p = __builtin_amdgcn_exp2f(s[n][r] - Mr);
            s[n][r] = p;
            rs += p;
          }
        }
        // n > nlim: s[n] stays 0 -> zero P columns (PV-safe)
      }
      rs += __shfl_xor(rs, 16);
      rs += __shfl_xor(rs, 32);
      Lr += rs;

      // packed P write: row q=l15, cols kv = n*16 + g*4 .. +3 (b64 each)
#pragma unroll
      for (int n = 0; n < 4; ++n) {
        const unsigned u0 = cvtpk_bf16(s[n][0], s[n][1]);
        const unsigned u1 = cvtpk_bf16(s[n][2], s[n][3]);
        *(uint2*)&Pw[l15 * 72 + n * 16 + (g << 2)] = make_uint2(u0, u1);
      }

      // PV: A = P (row=q=l15, k=kk*32+g*8+j), B = V^T (col(d)=l15)
#pragma unroll
      for (int kk = 0; kk < 2; ++kk) {
        const short8_t pf = *(const short8_t*)&Pw[l15 * 72 + kk * 32 + g * 8];
#pragma unroll
        for (int n = 0; n < 4; ++n) {
          const short8_t vf = *(const short8_t*)&Vc[vv_idx(n * 16 + l15, kk * 4 + g)];
          O[n] = __builtin_amdgcn_mfma_f32_16x16x32_bf16(pf, vf, O[n], 0, 0, 0);
        }
      }
    }

    // epilogue: O rows are q = g*4+r; stats live at lane l15=q
    const float inv = 1.0f / Lr;
    float invq[4];
#pragma unroll
    for (int r = 0; r < 4; ++r) invq[r] = __shfl(inv, (g << 2) + r);
#pragma unroll
    for (int n = 0; n < 4; ++n)
#pragma unroll
      for (int r = 0; r < 4; ++r) {
        const size_t row = (size_t)(b * TSEQ + wq0 + (g << 2) + r);
        yb[row * CDIM + h * HDIM + n * 16 + l15] = f2bf(O[n][r] * invq[r]);
      }
  }
}

// ---------------------------------------------------------------------------
extern "C" void kernel_launch(void* const* d_in, const int* in_sizes, int n_in,
                              void* d_out, int out_size, void* d_ws, size_t ws_size,
                              hipStream_t stream)
{
  const float* x     = (const float*)d_in[0];   // [B,T,C] fp32
  const float* Wqkv  = (const float*)d_in[1];   // [3C,C]  fp32
  const float* bqkv  = (const float*)d_in[2];   // [3C]
  const float* Wproj = (const float*)d_in[3];   // [C,C]
  const float* bproj = (const float*)d_in[4];   // [C]
  float* out = (float*)d_out;                   // [B,T,C] fp32

  const int M = BDIM * TSEQ;                    // 4096
  unsigned short* qkv = (unsigned short*)d_ws;          // M x 3C
  unsigned short* yb  = qkv + (size_t)M * C3;           // M x C
  unsigned short* xb  = yb  + (size_t)M * CDIM;         // M x C
  unsigned short* wqb = xb  + (size_t)M * CDIM;         // 3C x C
  unsigned short* wpb = wqb + (size_t)C3 * CDIM;        // C x C

  // 0) fp32 -> bf16 pre-conversion (RNE)
  f32_to_bf16<<<(M * CDIM / 4 + 255) / 256, 256, 0, stream>>>(x, xb, M * CDIM / 4);
  f32_to_bf16<<<(C3 * CDIM / 4 + 255) / 256, 256, 0, stream>>>(Wqkv, wqb, C3 * CDIM / 4);
  f32_to_bf16<<<(CDIM * CDIM / 4 + 255) / 256, 256, 0, stream>>>(Wproj, wpb, CDIM * CDIM / 4);

  // 1) qkv = bf16(x @ Wqkv^T + bqkv)
  gemm_bt_mfma<true><<<dim3(C3 / 128, M / 128), 256, 0, stream>>>(
      xb, wqb, bqkv, (void*)qkv, M, C3, CDIM);

  // 2) causal attention -> yb (bf16)
  attn_mfma<<<dim3(16, NHEAD, BDIM), 256, 0, stream>>>(qkv, yb);

  // 3) out = yb @ Wproj^T + bproj (fp32 out)
  gemm_bt_mfma<false><<<dim3(CDIM / 128, M / 128), 256, 0, stream>>>(
      yb, wpb, bproj, (void*)out, M, CDIM, CDIM);
}